// Round 8
// baseline (1527.905 us; speedup 1.0000x reference)
//
#include <hip/hip_runtime.h>
#include <hip/hip_fp16.h>
#include <math.h>

#define NN 100000
#define EE 1600000
#define HH 64
#define LL 8
#define NBLK ((NN + 1023) / 1024)
#define AGG_BLOCKS 2496

__device__ __forceinline__ float eluf(float x) { return x > 0.0f ? x : expm1f(x); }

// ================= CSR build (v2) =================

__global__ void count_edges_v2(const int* __restrict__ dst, int* __restrict__ counts) {
    int i = blockIdx.x * blockDim.x + threadIdx.x;
    if (i < EE) atomicAdd(&counts[dst[i]], 1);
}

__global__ void scan_block_v2(const int* __restrict__ counts, int* __restrict__ rp,
                              int* __restrict__ partial, float* __restrict__ dinv) {
    __shared__ int sm[256];
    const int t = threadIdx.x;
    const int base = blockIdx.x * 1024 + t * 4;
    int v0 = 0, v1 = 0, v2 = 0, v3 = 0;
    if (base + 0 < NN) v0 = counts[base + 0];
    if (base + 1 < NN) v1 = counts[base + 1];
    if (base + 2 < NN) v2 = counts[base + 2];
    if (base + 3 < NN) v3 = counts[base + 3];
    if (base + 0 < NN) dinv[base + 0] = rsqrtf((float)(v0 + 1));
    if (base + 1 < NN) dinv[base + 1] = rsqrtf((float)(v1 + 1));
    if (base + 2 < NN) dinv[base + 2] = rsqrtf((float)(v2 + 1));
    if (base + 3 < NN) dinv[base + 3] = rsqrtf((float)(v3 + 1));
    const int s = v0 + v1 + v2 + v3;
    sm[t] = s;
    __syncthreads();
    for (int off = 1; off < 256; off <<= 1) {
        int x = 0;
        if (t >= off) x = sm[t - off];
        __syncthreads();
        if (t >= off) sm[t] += x;
        __syncthreads();
    }
    int excl = sm[t] - s;
    if (t == 255) partial[blockIdx.x] = sm[255];
    if (base + 0 < NN) rp[base + 0] = excl;
    excl += v0;
    if (base + 1 < NN) rp[base + 1] = excl;
    excl += v1;
    if (base + 2 < NN) rp[base + 2] = excl;
    excl += v2;
    if (base + 3 < NN) rp[base + 3] = excl;
}

__global__ void scan_top_v2(int* partial) {
    __shared__ int sm[128];
    const int t = threadIdx.x;
    const int v = (t < NBLK) ? partial[t] : 0;
    sm[t] = v;
    __syncthreads();
    for (int off = 1; off < 128; off <<= 1) {
        int x = 0;
        if (t >= off) x = sm[t - off];
        __syncthreads();
        if (t >= off) sm[t] += x;
        __syncthreads();
    }
    if (t < NBLK) partial[t] = sm[t] - v;  // exclusive
}

__global__ void scan_add_v2(int* rp, const int* __restrict__ partial) {
    const int i = blockIdx.x * blockDim.x + threadIdx.x;
    if (i < NN) rp[i] += partial[i >> 10];
    else if (i == NN) rp[NN] = EE;
}

// col-only payload: 4B random write per edge (val factored out via pre-scaled rows)
__global__ void scatter_v2(const int* __restrict__ src, const int* __restrict__ dst,
                           const int* __restrict__ rp, int* __restrict__ fill,
                           int* __restrict__ col) {
    const int e = blockIdx.x * blockDim.x + threadIdx.x;
    if (e < EE) {
        const int d = dst[e];
        const int pos = rp[d] + atomicAdd(&fill[d], 1);
        col[pos] = src[e];
    }
}

// zero sentinel row NN of both fp16 gather buffers (masked lanes gather row NN)
__global__ void init_sent_v2(__half* a, __half* b) {
    const int t = threadIdx.x;
    if (t < 64) a[(size_t)NN * HH + t] = __float2half(0.f);
    else b[(size_t)NN * HH + (t - 64)] = __float2half(0.f);
}

// ================= aggregation: s = 0.5*di*(sum h~[src] + h~[self]) + 0.5*x0 =================
// One wave per node. 8 groups x 8 lanes; each lane covers an 8-feature chunk via
// 16B fp16 loads; 32 edges per j-step -> 4 gather rows in flight per lane
// (sentinel row NN zero-pads invalid slots: no inner bounds checks).
// Group 0 stores s (fp32).

__global__ __launch_bounds__(256) void agg_v2(
    const int* __restrict__ rp, const int* __restrict__ col, const float* __restrict__ dinv,
    const __half* __restrict__ hin, const float* __restrict__ x0, float* __restrict__ sout) {
    const int lane = threadIdx.x & 63;
    const int g = lane >> 3;         // group 0..7
    const int fc = (lane & 7) << 3;  // feature chunk base
    const int wave = blockIdx.x * 4 + (threadIdx.x >> 6);
    const int nwaves = gridDim.x * 4;

    for (int node = wave; node < NN; node += nwaves) {
        const int start = rp[node], end = rp[node + 1];
        float acc[8] = {};
        for (int e = start; e < end; e += 64) {
            const int me = e + lane;
            const int c = (me < end) ? col[me] : NN;  // sentinel row NN is all-zero
            int nb = end - e;
            if (nb > 64) nb = 64;
            const int it = (nb + 31) >> 5;  // 32 edges per j-step
            for (int j = 0; j < it; ++j) {
                const int b = j * 32 + g;
                const int c0 = __shfl(c, b, 64);
                const int c1 = __shfl(c, b + 8, 64);
                const int c2 = __shfl(c, b + 16, 64);
                const int c3 = __shfl(c, b + 24, 64);
                float4 r0 = *(const float4*)(hin + ((size_t)c0 << 6) + fc);
                float4 r1 = *(const float4*)(hin + ((size_t)c1 << 6) + fc);
                float4 r2 = *(const float4*)(hin + ((size_t)c2 << 6) + fc);
                float4 r3 = *(const float4*)(hin + ((size_t)c3 << 6) + fc);
                const __half2* h0 = (const __half2*)&r0;
                const __half2* h1 = (const __half2*)&r1;
                const __half2* h2 = (const __half2*)&r2;
                const __half2* h3 = (const __half2*)&r3;
#pragma unroll
                for (int q = 0; q < 4; ++q) {
                    const float2 f0 = __half22float2(h0[q]);
                    const float2 f1 = __half22float2(h1[q]);
                    const float2 f2 = __half22float2(h2[q]);
                    const float2 f3 = __half22float2(h3[q]);
                    acc[2 * q] += (f0.x + f1.x) + (f2.x + f3.x);
                    acc[2 * q + 1] += (f0.y + f1.y) + (f2.y + f3.y);
                }
            }
        }
        // reduce the 8 groups (lane bits 3..5)
#pragma unroll
        for (int m = 8; m <= 32; m <<= 1)
#pragma unroll
            for (int q = 0; q < 8; ++q) acc[q] += __shfl_xor(acc[q], m, 64);
        if (g == 0) {  // lanes 0..7 hold full sums for chunks 0..7
            // self loop: h~[self] = di*h[self]
            float4 r = *(const float4*)(hin + ((size_t)node << 6) + fc);
            const __half2* hh = (const __half2*)&r;
#pragma unroll
            for (int q = 0; q < 4; ++q) {
                const float2 f = __half22float2(hh[q]);
                acc[2 * q] += f.x;
                acc[2 * q + 1] += f.y;
            }
            const float di = dinv[node];
            const float4* xp = (const float4*)(x0 + ((size_t)node << 6) + fc);
            const float4 xa = xp[0], xb = xp[1];
            float4 oa, ob;
            oa.x = 0.5f * fmaf(di, acc[0], xa.x);
            oa.y = 0.5f * fmaf(di, acc[1], xa.y);
            oa.z = 0.5f * fmaf(di, acc[2], xa.z);
            oa.w = 0.5f * fmaf(di, acc[3], xa.w);
            ob.x = 0.5f * fmaf(di, acc[4], xb.x);
            ob.y = 0.5f * fmaf(di, acc[5], xb.y);
            ob.z = 0.5f * fmaf(di, acc[6], xb.z);
            ob.w = 0.5f * fmaf(di, acc[7], xb.w);
            float4* sp = (float4*)(sout + ((size_t)node << 6) + fc);
            sp[0] = oa;
            sp[1] = ob;
        }
    }
}

// ================= layer GEMM: o = s @ (beta*W + (1-beta)*I); h = elu(o)+o =================
// out16 = half(dinv[r]*h) [pre-scaled for next gather]; optional fp32 h written
// in-place into A (safe: single K-chunk, each block stages its own rows first).

__global__ __launch_bounds__(256) void lgemm_v2(const float* __restrict__ A,
                                                const float* __restrict__ W,
                                                const float* __restrict__ dinvp, float beta,
                                                __half* __restrict__ out16,
                                                float* __restrict__ out32, int w32) {
    __shared__ float ss[64][68];
    __shared__ float ws[64][64];
    const int t = threadIdx.x;
    const int row0 = blockIdx.x * 64;
    const int tx = t & 15, ty = t >> 4;
    float acc[4][4] = {};
    const float ob = 1.0f - beta;

#pragma unroll
    for (int i = 0; i < 4; ++i) {
        const int linear = t + i * 256;
        const int r = linear >> 4, q = linear & 15;
        const int grow = row0 + r;
        float4 v = make_float4(0.f, 0.f, 0.f, 0.f);
        if (grow < NN) v = *(const float4*)&A[(size_t)grow * 64 + q * 4];
        *(float4*)&ss[r][q * 4] = v;
    }
#pragma unroll
    for (int i = 0; i < 4; ++i) {
        const int linear = t + i * 256;
        const int r = linear >> 4, q = linear & 15;
        float4 v = *(const float4*)&W[(size_t)r * 64 + q * 4];
        v.x = v.x * beta + ((q * 4 + 0 == r) ? ob : 0.f);
        v.y = v.y * beta + ((q * 4 + 1 == r) ? ob : 0.f);
        v.z = v.z * beta + ((q * 4 + 2 == r) ? ob : 0.f);
        v.w = v.w * beta + ((q * 4 + 3 == r) ? ob : 0.f);
        *(float4*)&ws[r][q * 4] = v;
    }
    __syncthreads();
#pragma unroll
    for (int k = 0; k < 64; k += 4) {
        float4 af[4], bf[4];
        af[0] = *(const float4*)&ss[ty * 4 + 0][k];
        af[1] = *(const float4*)&ss[ty * 4 + 1][k];
        af[2] = *(const float4*)&ss[ty * 4 + 2][k];
        af[3] = *(const float4*)&ss[ty * 4 + 3][k];
        bf[0] = *(const float4*)&ws[k + 0][tx * 4];
        bf[1] = *(const float4*)&ws[k + 1][tx * 4];
        bf[2] = *(const float4*)&ws[k + 2][tx * 4];
        bf[3] = *(const float4*)&ws[k + 3][tx * 4];
        const float* A4 = (const float*)af;
        const float* B4 = (const float*)bf;
#pragma unroll
        for (int i = 0; i < 4; ++i)
#pragma unroll
            for (int kk = 0; kk < 4; ++kk)
#pragma unroll
                for (int j = 0; j < 4; ++j)
                    acc[i][j] = fmaf(A4[i * 4 + kk], B4[kk * 4 + j], acc[i][j]);
    }

#pragma unroll
    for (int i = 0; i < 4; ++i) {
        const int r = row0 + ty * 4 + i;
        if (r >= NN) continue;
        const float dv = dinvp[r];
        float hv[4];
#pragma unroll
        for (int j = 0; j < 4; ++j) {
            const float o = acc[i][j];
            hv[j] = eluf(o) + o;
        }
        __half2* hp = (__half2*)&out16[(size_t)r * 64 + tx * 4];
        hp[0] = __floats2half2_rn(hv[0] * dv, hv[1] * dv);
        hp[1] = __floats2half2_rn(hv[2] * dv, hv[3] * dv);
        if (w32) {
            *(float4*)&out32[(size_t)r * 64 + tx * 4] = make_float4(hv[0], hv[1], hv[2], hv[3]);
        }
    }
}

// ================= dense GEMM for input/output layers =================
// MODE 0: out32 = elu(A@B + bias); out16 = half(dinv[r] * out32)   (KTOT=256)
// MODE 2: out32 = A@B + bias                                       (KTOT=64)

template <int KTOT, int MODE>
__global__ __launch_bounds__(256) void gemm_v2(const float* __restrict__ A,
                                               const float* __restrict__ B,
                                               const float* __restrict__ bias,
                                               const float* __restrict__ dinvp,
                                               float* __restrict__ out32,
                                               __half* __restrict__ out16) {
    __shared__ float ss[64][68];
    __shared__ float ws[64][64];
    const int t = threadIdx.x;
    const int row0 = blockIdx.x * 64;
    const int tx = t & 15, ty = t >> 4;
    float acc[4][4] = {};

    for (int kc = 0; kc < KTOT; kc += 64) {
#pragma unroll
        for (int i = 0; i < 4; ++i) {
            const int linear = t + i * 256;
            const int r = linear >> 4, q = linear & 15;
            const int grow = row0 + r;
            float4 v = make_float4(0.f, 0.f, 0.f, 0.f);
            if (grow < NN) v = *(const float4*)&A[(size_t)grow * KTOT + kc + q * 4];
            *(float4*)&ss[r][q * 4] = v;
        }
#pragma unroll
        for (int i = 0; i < 4; ++i) {
            const int linear = t + i * 256;
            const int r = linear >> 4, q = linear & 15;
            *(float4*)&ws[r][q * 4] = *(const float4*)&B[(size_t)(kc + r) * 64 + q * 4];
        }
        __syncthreads();
#pragma unroll
        for (int k = 0; k < 64; k += 4) {
            float4 af[4], bf[4];
            af[0] = *(const float4*)&ss[ty * 4 + 0][k];
            af[1] = *(const float4*)&ss[ty * 4 + 1][k];
            af[2] = *(const float4*)&ss[ty * 4 + 2][k];
            af[3] = *(const float4*)&ss[ty * 4 + 3][k];
            bf[0] = *(const float4*)&ws[k + 0][tx * 4];
            bf[1] = *(const float4*)&ws[k + 1][tx * 4];
            bf[2] = *(const float4*)&ws[k + 2][tx * 4];
            bf[3] = *(const float4*)&ws[k + 3][tx * 4];
            const float* A4 = (const float*)af;
            const float* B4 = (const float*)bf;
#pragma unroll
            for (int i = 0; i < 4; ++i)
#pragma unroll
                for (int kk = 0; kk < 4; ++kk)
#pragma unroll
                    for (int j = 0; j < 4; ++j)
                        acc[i][j] = fmaf(A4[i * 4 + kk], B4[kk * 4 + j], acc[i][j]);
        }
        __syncthreads();
    }

#pragma unroll
    for (int i = 0; i < 4; ++i) {
        const int r = row0 + ty * 4 + i;
        if (r >= NN) continue;
        float4 o;
        float* op = (float*)&o;
#pragma unroll
        for (int j = 0; j < 4; ++j) {
            float xv = acc[i][j] + bias[tx * 4 + j];
            if (MODE == 0) xv = eluf(xv);
            op[j] = xv;
        }
        *(float4*)&out32[(size_t)r * 64 + tx * 4] = o;
        if (MODE == 0) {
            const float dv = dinvp[r];
            __half2* hp = (__half2*)&out16[(size_t)r * 64 + tx * 4];
            hp[0] = __floats2half2_rn(o.x * dv, o.y * dv);
            hp[1] = __floats2half2_rn(o.z * dv, o.w * dv);
        }
    }
}

// ================= launch =================

extern "C" void kernel_launch(void* const* d_in, const int* in_sizes, int n_in, void* d_out,
                              int out_size, void* d_ws, size_t ws_size, hipStream_t stream) {
    const float* x = (const float*)d_in[0];
    const int* ei = (const int*)d_in[1];
    const float* w_in = (const float*)d_in[2];
    const float* b_in = (const float*)d_in[3];
    const float* w_layers = (const float*)d_in[4];
    const float* w_out = (const float*)d_in[5];
    const float* b_out = (const float*)d_in[6];
    float* out = (float*)d_out;

    char* p = (char*)d_ws;
    auto alloc = [&](size_t bytes) -> char* {
        char* r = p;
        p += (bytes + 255) & ~(size_t)255;
        return r;
    };
    int* counts = (int*)alloc((size_t)NN * 4);
    int* fill = (int*)alloc((size_t)NN * 4);
    int* rp = (int*)alloc((size_t)(NN + 1) * 4);
    int* partial = (int*)alloc(128 * 4);
    float* dinv = (float*)alloc((size_t)NN * 4);
    int* colA = (int*)alloc((size_t)EE * 4);
    float* x0 = (float*)alloc((size_t)NN * HH * 4);           // fp32 residual
    __half* x0h = (__half*)alloc((size_t)(NN + 1) * HH * 2);  // scaled gather buf A
    __half* hA = (__half*)alloc((size_t)(NN + 1) * HH * 2);   // scaled gather buf B
    float* sbuf = (float*)alloc((size_t)NN * HH * 4);         // fp32 s / final fp32 h

    const int* srcA = ei;
    const int* dstA = ei + EE;

    hipMemsetAsync(counts, 0, (size_t)NN * 4, stream);
    hipMemsetAsync(fill, 0, (size_t)NN * 4, stream);
    init_sent_v2<<<1, 128, 0, stream>>>(x0h, hA);
    count_edges_v2<<<(EE + 255) / 256, 256, 0, stream>>>(dstA, counts);
    scan_block_v2<<<NBLK, 256, 0, stream>>>(counts, rp, partial, dinv);
    scan_top_v2<<<1, 128, 0, stream>>>(partial);
    scan_add_v2<<<(NN + 1 + 255) / 256, 256, 0, stream>>>(rp, partial);
    scatter_v2<<<(EE + 255) / 256, 256, 0, stream>>>(srcA, dstA, rp, fill, colA);

    // x0 = elu(x @ w_in + b_in);  x0h = half(dinv * x0)
    gemm_v2<256, 0><<<(NN + 63) / 64, 256, 0, stream>>>(x, w_in, b_in, dinv, x0, x0h);

    for (int l = 0; l < LL; ++l) {
        const float beta = (float)log(1.0 / (double)(l + 1) + 1.0);
        const __half* hin = (l & 1) ? hA : x0h;  // l=0 reads x0h
        __half* hout = (l & 1) ? x0h : hA;
        agg_v2<<<AGG_BLOCKS, 256, 0, stream>>>(rp, colA, dinv, hin, x0, sbuf);
        lgemm_v2<<<(NN + 63) / 64, 256, 0, stream>>>(sbuf, w_layers + (size_t)l * 64 * 64, dinv,
                                                     beta, hout, sbuf, l == LL - 1);
    }
    gemm_v2<64, 2><<<(NN + 63) / 64, 256, 0, stream>>>(sbuf, w_out, b_out, nullptr, out, nullptr);
}

// Round 9
// 918.813 us; speedup vs baseline: 1.6629x; 1.6629x over previous
//
#include <hip/hip_runtime.h>
#include <hip/hip_fp16.h>
#include <math.h>

#define NN 100000
#define EE 1600000
#define HH 64
#define LL 8
#define NBLK ((NN + 1023) / 1024)
#define AGG_BLOCKS 2496

__device__ __forceinline__ float eluf(float x) { return x > 0.0f ? x : expm1f(x); }

// ================= CSR build =================

__global__ void count_edges_v2(const int* __restrict__ dst, int* __restrict__ counts) {
    int i = blockIdx.x * blockDim.x + threadIdx.x;
    if (i < EE) atomicAdd(&counts[dst[i]], 1);
}

__global__ void scan_block_v2(const int* __restrict__ counts, int* __restrict__ rp,
                              int* __restrict__ partial, float* __restrict__ dinv) {
    __shared__ int sm[256];
    const int t = threadIdx.x;
    const int base = blockIdx.x * 1024 + t * 4;
    int v0 = 0, v1 = 0, v2 = 0, v3 = 0;
    if (base + 0 < NN) v0 = counts[base + 0];
    if (base + 1 < NN) v1 = counts[base + 1];
    if (base + 2 < NN) v2 = counts[base + 2];
    if (base + 3 < NN) v3 = counts[base + 3];
    if (base + 0 < NN) dinv[base + 0] = rsqrtf((float)(v0 + 1));
    if (base + 1 < NN) dinv[base + 1] = rsqrtf((float)(v1 + 1));
    if (base + 2 < NN) dinv[base + 2] = rsqrtf((float)(v2 + 1));
    if (base + 3 < NN) dinv[base + 3] = rsqrtf((float)(v3 + 1));
    const int s = v0 + v1 + v2 + v3;
    sm[t] = s;
    __syncthreads();
    for (int off = 1; off < 256; off <<= 1) {
        int x = 0;
        if (t >= off) x = sm[t - off];
        __syncthreads();
        if (t >= off) sm[t] += x;
        __syncthreads();
    }
    int excl = sm[t] - s;
    if (t == 255) partial[blockIdx.x] = sm[255];
    if (base + 0 < NN) rp[base + 0] = excl;
    excl += v0;
    if (base + 1 < NN) rp[base + 1] = excl;
    excl += v1;
    if (base + 2 < NN) rp[base + 2] = excl;
    excl += v2;
    if (base + 3 < NN) rp[base + 3] = excl;
}

__global__ void scan_top_v2(int* partial) {
    __shared__ int sm[128];
    const int t = threadIdx.x;
    const int v = (t < NBLK) ? partial[t] : 0;
    sm[t] = v;
    __syncthreads();
    for (int off = 1; off < 128; off <<= 1) {
        int x = 0;
        if (t >= off) x = sm[t - off];
        __syncthreads();
        if (t >= off) sm[t] += x;
        __syncthreads();
    }
    if (t < NBLK) partial[t] = sm[t] - v;  // exclusive
}

__global__ void scan_add_v2(int* rp, const int* __restrict__ partial) {
    const int i = blockIdx.x * blockDim.x + threadIdx.x;
    if (i < NN) rp[i] += partial[i >> 10];
    else if (i == NN) rp[NN] = EE;
}

// col-only payload: 4B random write per edge (val factored out via pre-scaled rows)
__global__ void scatter_v2(const int* __restrict__ src, const int* __restrict__ dst,
                           const int* __restrict__ rp, int* __restrict__ fill,
                           int* __restrict__ col) {
    const int e = blockIdx.x * blockDim.x + threadIdx.x;
    if (e < EE) {
        const int d = dst[e];
        const int pos = rp[d] + atomicAdd(&fill[d], 1);
        col[pos] = src[e];
    }
}

// zero sentinel row NN of both fp16 gather buffers (masked lanes gather row NN)
__global__ void init_sent_v2(__half* a, __half* b) {
    const int t = threadIdx.x;
    if (t < 64) a[(size_t)NN * HH + t] = __float2half(0.f);
    else b[(size_t)NN * HH + (t - 64)] = __float2half(0.f);
}

// ================= aggregation: s = 0.5*di*(sum h~[src] + h~[self]) + 0.5*x0 =================
// One wave per node. 8 groups x 8 lanes; each lane covers an 8-feature chunk via
// 16B fp16 loads; 32 edges per j-step -> 4 gather rows in flight per lane.

__global__ __launch_bounds__(256) void agg_v2(
    const int* __restrict__ rp, const int* __restrict__ col, const float* __restrict__ dinv,
    const __half* __restrict__ hin, const float* __restrict__ x0, float* __restrict__ sout) {
    const int lane = threadIdx.x & 63;
    const int g = lane >> 3;         // group 0..7
    const int fc = (lane & 7) << 3;  // feature chunk base
    const int wave = blockIdx.x * 4 + (threadIdx.x >> 6);
    const int nwaves = gridDim.x * 4;

    for (int node = wave; node < NN; node += nwaves) {
        const int start = rp[node], end = rp[node + 1];
        float acc[8] = {};
        for (int e = start; e < end; e += 64) {
            const int me = e + lane;
            const int c = (me < end) ? col[me] : NN;  // sentinel row NN is all-zero
            int nb = end - e;
            if (nb > 64) nb = 64;
            const int it = (nb + 31) >> 5;  // 32 edges per j-step
            for (int j = 0; j < it; ++j) {
                const int b = j * 32 + g;
                const int c0 = __shfl(c, b, 64);
                const int c1 = __shfl(c, b + 8, 64);
                const int c2 = __shfl(c, b + 16, 64);
                const int c3 = __shfl(c, b + 24, 64);
                float4 r0 = *(const float4*)(hin + ((size_t)c0 << 6) + fc);
                float4 r1 = *(const float4*)(hin + ((size_t)c1 << 6) + fc);
                float4 r2 = *(const float4*)(hin + ((size_t)c2 << 6) + fc);
                float4 r3 = *(const float4*)(hin + ((size_t)c3 << 6) + fc);
                const __half2* h0 = (const __half2*)&r0;
                const __half2* h1 = (const __half2*)&r1;
                const __half2* h2 = (const __half2*)&r2;
                const __half2* h3 = (const __half2*)&r3;
#pragma unroll
                for (int q = 0; q < 4; ++q) {
                    const float2 f0 = __half22float2(h0[q]);
                    const float2 f1 = __half22float2(h1[q]);
                    const float2 f2 = __half22float2(h2[q]);
                    const float2 f3 = __half22float2(h3[q]);
                    acc[2 * q] += (f0.x + f1.x) + (f2.x + f3.x);
                    acc[2 * q + 1] += (f0.y + f1.y) + (f2.y + f3.y);
                }
            }
        }
        // reduce the 8 groups (lane bits 3..5)
#pragma unroll
        for (int m = 8; m <= 32; m <<= 1)
#pragma unroll
            for (int q = 0; q < 8; ++q) acc[q] += __shfl_xor(acc[q], m, 64);
        if (g == 0) {  // lanes 0..7 hold full sums for chunks 0..7
            float4 r = *(const float4*)(hin + ((size_t)node << 6) + fc);
            const __half2* hh = (const __half2*)&r;
#pragma unroll
            for (int q = 0; q < 4; ++q) {
                const float2 f = __half22float2(hh[q]);
                acc[2 * q] += f.x;
                acc[2 * q + 1] += f.y;
            }
            const float di = dinv[node];
            const float4* xp = (const float4*)(x0 + ((size_t)node << 6) + fc);
            const float4 xa = xp[0], xb = xp[1];
            float4 oa, ob;
            oa.x = 0.5f * fmaf(di, acc[0], xa.x);
            oa.y = 0.5f * fmaf(di, acc[1], xa.y);
            oa.z = 0.5f * fmaf(di, acc[2], xa.z);
            oa.w = 0.5f * fmaf(di, acc[3], xa.w);
            ob.x = 0.5f * fmaf(di, acc[4], xb.x);
            ob.y = 0.5f * fmaf(di, acc[5], xb.y);
            ob.z = 0.5f * fmaf(di, acc[6], xb.z);
            ob.w = 0.5f * fmaf(di, acc[7], xb.w);
            float4* sp = (float4*)(sout + ((size_t)node << 6) + fc);
            sp[0] = oa;
            sp[1] = ob;
        }
    }
}

// ================= layer GEMM: o = s @ (beta*W + (1-beta)*I); h = elu(o)+o =================
// R8 post-mortem: unbounded codegen flattened the k-loop, hit 256 VGPRs and
// spilled to scratch (WRITE_SIZE 27.5MB vs 12.8 expected, occupancy 10%,
// 107us/dispatch). Fix: __launch_bounds__(256,4) caps VGPRs ~128; unroll 4
// keeps the scheduler in small windows. Live set ~80 regs -> no spill.

__global__ __launch_bounds__(256, 4) void lgemm_v3(const float* __restrict__ A,
                                                   const float* __restrict__ W,
                                                   const float* __restrict__ dinvp, float beta,
                                                   __half* __restrict__ out16,
                                                   float* __restrict__ out32, int w32) {
    __shared__ float ss[64][68];
    __shared__ float ws[64][64];
    const int t = threadIdx.x;
    const int row0 = blockIdx.x * 64;
    const int tx = t & 15, ty = t >> 4;
    float acc[4][4] = {};
    const float ob = 1.0f - beta;

#pragma unroll
    for (int i = 0; i < 4; ++i) {
        const int linear = t + i * 256;
        const int r = linear >> 4, q = linear & 15;
        const int grow = row0 + r;
        float4 v = make_float4(0.f, 0.f, 0.f, 0.f);
        if (grow < NN) v = *(const float4*)&A[(size_t)grow * 64 + q * 4];
        *(float4*)&ss[r][q * 4] = v;
    }
#pragma unroll
    for (int i = 0; i < 4; ++i) {
        const int linear = t + i * 256;
        const int r = linear >> 4, q = linear & 15;
        float4 v = *(const float4*)&W[(size_t)r * 64 + q * 4];
        v.x = v.x * beta + ((q * 4 + 0 == r) ? ob : 0.f);
        v.y = v.y * beta + ((q * 4 + 1 == r) ? ob : 0.f);
        v.z = v.z * beta + ((q * 4 + 2 == r) ? ob : 0.f);
        v.w = v.w * beta + ((q * 4 + 3 == r) ? ob : 0.f);
        *(float4*)&ws[r][q * 4] = v;
    }
    __syncthreads();
#pragma unroll 4
    for (int k = 0; k < 64; k += 4) {
        float4 af[4], bf[4];
        af[0] = *(const float4*)&ss[ty * 4 + 0][k];
        af[1] = *(const float4*)&ss[ty * 4 + 1][k];
        af[2] = *(const float4*)&ss[ty * 4 + 2][k];
        af[3] = *(const float4*)&ss[ty * 4 + 3][k];
        bf[0] = *(const float4*)&ws[k + 0][tx * 4];
        bf[1] = *(const float4*)&ws[k + 1][tx * 4];
        bf[2] = *(const float4*)&ws[k + 2][tx * 4];
        bf[3] = *(const float4*)&ws[k + 3][tx * 4];
        const float* A4 = (const float*)af;
        const float* B4 = (const float*)bf;
#pragma unroll
        for (int i = 0; i < 4; ++i)
#pragma unroll
            for (int kk = 0; kk < 4; ++kk)
#pragma unroll
                for (int j = 0; j < 4; ++j)
                    acc[i][j] = fmaf(A4[i * 4 + kk], B4[kk * 4 + j], acc[i][j]);
    }

#pragma unroll
    for (int i = 0; i < 4; ++i) {
        const int r = row0 + ty * 4 + i;
        if (r >= NN) continue;
        const float dv = dinvp[r];
        const float o0 = acc[i][0], o1 = acc[i][1], o2 = acc[i][2], o3 = acc[i][3];
        const float h0 = eluf(o0) + o0;
        const float h1 = eluf(o1) + o1;
        const float h2 = eluf(o2) + o2;
        const float h3 = eluf(o3) + o3;
        __half2* hp = (__half2*)&out16[(size_t)r * 64 + tx * 4];
        hp[0] = __floats2half2_rn(h0 * dv, h1 * dv);
        hp[1] = __floats2half2_rn(h2 * dv, h3 * dv);
        if (w32) {
            *(float4*)&out32[(size_t)r * 64 + tx * 4] = make_float4(h0, h1, h2, h3);
        }
    }
}

// ================= dense GEMM for input/output layers =================
// MODE 0: out32 = elu(A@B + bias); out16 = half(dinv[r] * out32)   (KTOT=256)
// MODE 2: out32 = A@B + bias                                       (KTOT=64)

template <int KTOT, int MODE>
__global__ __launch_bounds__(256, 4) void gemm_v2(const float* __restrict__ A,
                                                  const float* __restrict__ B,
                                                  const float* __restrict__ bias,
                                                  const float* __restrict__ dinvp,
                                                  float* __restrict__ out32,
                                                  __half* __restrict__ out16) {
    __shared__ float ss[64][68];
    __shared__ float ws[64][64];
    const int t = threadIdx.x;
    const int row0 = blockIdx.x * 64;
    const int tx = t & 15, ty = t >> 4;
    float acc[4][4] = {};

    for (int kc = 0; kc < KTOT; kc += 64) {
#pragma unroll
        for (int i = 0; i < 4; ++i) {
            const int linear = t + i * 256;
            const int r = linear >> 4, q = linear & 15;
            const int grow = row0 + r;
            float4 v = make_float4(0.f, 0.f, 0.f, 0.f);
            if (grow < NN) v = *(const float4*)&A[(size_t)grow * KTOT + kc + q * 4];
            *(float4*)&ss[r][q * 4] = v;
        }
#pragma unroll
        for (int i = 0; i < 4; ++i) {
            const int linear = t + i * 256;
            const int r = linear >> 4, q = linear & 15;
            *(float4*)&ws[r][q * 4] = *(const float4*)&B[(size_t)(kc + r) * 64 + q * 4];
        }
        __syncthreads();
#pragma unroll 4
        for (int k = 0; k < 64; k += 4) {
            float4 af[4], bf[4];
            af[0] = *(const float4*)&ss[ty * 4 + 0][k];
            af[1] = *(const float4*)&ss[ty * 4 + 1][k];
            af[2] = *(const float4*)&ss[ty * 4 + 2][k];
            af[3] = *(const float4*)&ss[ty * 4 + 3][k];
            bf[0] = *(const float4*)&ws[k + 0][tx * 4];
            bf[1] = *(const float4*)&ws[k + 1][tx * 4];
            bf[2] = *(const float4*)&ws[k + 2][tx * 4];
            bf[3] = *(const float4*)&ws[k + 3][tx * 4];
            const float* A4 = (const float*)af;
            const float* B4 = (const float*)bf;
#pragma unroll
            for (int i = 0; i < 4; ++i)
#pragma unroll
                for (int kk = 0; kk < 4; ++kk)
#pragma unroll
                    for (int j = 0; j < 4; ++j)
                        acc[i][j] = fmaf(A4[i * 4 + kk], B4[kk * 4 + j], acc[i][j]);
        }
        __syncthreads();
    }

#pragma unroll
    for (int i = 0; i < 4; ++i) {
        const int r = row0 + ty * 4 + i;
        if (r >= NN) continue;
        float4 o;
        float* op = (float*)&o;
#pragma unroll
        for (int j = 0; j < 4; ++j) {
            float xv = acc[i][j] + bias[tx * 4 + j];
            if (MODE == 0) xv = eluf(xv);
            op[j] = xv;
        }
        *(float4*)&out32[(size_t)r * 64 + tx * 4] = o;
        if (MODE == 0) {
            const float dv = dinvp[r];
            __half2* hp = (__half2*)&out16[(size_t)r * 64 + tx * 4];
            hp[0] = __floats2half2_rn(o.x * dv, o.y * dv);
            hp[1] = __floats2half2_rn(o.z * dv, o.w * dv);
        }
    }
}

// ================= launch =================

extern "C" void kernel_launch(void* const* d_in, const int* in_sizes, int n_in, void* d_out,
                              int out_size, void* d_ws, size_t ws_size, hipStream_t stream) {
    const float* x = (const float*)d_in[0];
    const int* ei = (const int*)d_in[1];
    const float* w_in = (const float*)d_in[2];
    const float* b_in = (const float*)d_in[3];
    const float* w_layers = (const float*)d_in[4];
    const float* w_out = (const float*)d_in[5];
    const float* b_out = (const float*)d_in[6];
    float* out = (float*)d_out;

    char* p = (char*)d_ws;
    auto alloc = [&](size_t bytes) -> char* {
        char* r = p;
        p += (bytes + 255) & ~(size_t)255;
        return r;
    };
    int* counts = (int*)alloc((size_t)NN * 4);
    int* fill = (int*)alloc((size_t)NN * 4);
    int* rp = (int*)alloc((size_t)(NN + 1) * 4);
    int* partial = (int*)alloc(128 * 4);
    float* dinv = (float*)alloc((size_t)NN * 4);
    int* colA = (int*)alloc((size_t)EE * 4);
    float* x0 = (float*)alloc((size_t)NN * HH * 4);           // fp32 residual
    __half* x0h = (__half*)alloc((size_t)(NN + 1) * HH * 2);  // scaled gather buf A
    __half* hA = (__half*)alloc((size_t)(NN + 1) * HH * 2);   // scaled gather buf B
    float* sbuf = (float*)alloc((size_t)NN * HH * 4);         // fp32 s / final fp32 h

    const int* srcA = ei;
    const int* dstA = ei + EE;

    hipMemsetAsync(counts, 0, (size_t)NN * 4, stream);
    hipMemsetAsync(fill, 0, (size_t)NN * 4, stream);
    init_sent_v2<<<1, 128, 0, stream>>>(x0h, hA);
    count_edges_v2<<<(EE + 255) / 256, 256, 0, stream>>>(dstA, counts);
    scan_block_v2<<<NBLK, 256, 0, stream>>>(counts, rp, partial, dinv);
    scan_top_v2<<<1, 128, 0, stream>>>(partial);
    scan_add_v2<<<(NN + 1 + 255) / 256, 256, 0, stream>>>(rp, partial);
    scatter_v2<<<(EE + 255) / 256, 256, 0, stream>>>(srcA, dstA, rp, fill, colA);

    // x0 = elu(x @ w_in + b_in);  x0h = half(dinv * x0)
    gemm_v2<256, 0><<<(NN + 63) / 64, 256, 0, stream>>>(x, w_in, b_in, dinv, x0, x0h);

    for (int l = 0; l < LL; ++l) {
        const float beta = (float)log(1.0 / (double)(l + 1) + 1.0);
        const __half* hin = (l & 1) ? hA : x0h;  // l=0 reads x0h
        __half* hout = (l & 1) ? x0h : hA;
        agg_v2<<<AGG_BLOCKS, 256, 0, stream>>>(rp, colA, dinv, hin, x0, sbuf);
        lgemm_v3<<<(NN + 63) / 64, 256, 0, stream>>>(sbuf, w_layers + (size_t)l * 64 * 64, dinv,
                                                     beta, hout, sbuf, l == LL - 1);
    }
    gemm_v2<64, 2><<<(NN + 63) / 64, 256, 0, stream>>>(sbuf, w_out, b_out, nullptr, out, nullptr);
}